// Round 4
// baseline (128.590 us; speedup 1.0000x reference)
//
#include <hip/hip_runtime.h>
#include <math.h>

// Problem constants (setup_inputs: S=2048, U=10, D=256)
#define SS   2048
#define UU   10
#define DD   256
#define BB   (SS * UU)   // 20480 rows
#define EPSF 1e-8f

typedef __attribute__((ext_vector_type(8)))  short  bf16x8;
typedef __attribute__((ext_vector_type(16))) float  floatx16;

__device__ static inline unsigned short f2bf(float f) {
    union { float f; unsigned u; } v; v.f = f;
    unsigned r = (v.u + 0x7FFFu + ((v.u >> 16) & 1u)) >> 16;  // RNE
    return (unsigned short)r;
}

__device__ static inline void gl_lds16(const unsigned short* g, unsigned short* l) {
    // 16B per lane; LDS dest = wave-uniform base + lane*16
    __builtin_amdgcn_global_load_lds((const __attribute__((address_space(1))) void*)g,
                                     (__attribute__((address_space(3))) void*)l, 16, 0, 0);
}

// ---- Kernel 1 (fused prep): normalize rows -> Enb, centroid+normalize -> Cnb ----
__global__ __launch_bounds__(256) void prep_kernel(const float* __restrict__ E,
                                                   unsigned short* __restrict__ Enb,
                                                   unsigned short* __restrict__ Cnb) {
    const int s   = blockIdx.x;
    const int wid = threadIdx.x >> 6, lane = threadIdx.x & 63;
    __shared__ float cent[4][256];
    __shared__ float sred[256];

    float cp0 = 0.f, cp1 = 0.f, cp2 = 0.f, cp3 = 0.f;
    for (int u = wid; u < UU; u += 4) {
        const size_t roff = (size_t)(s * UU + u) * DD;
        float4 v = ((const float4*)(E + roff))[lane];
        float ssq = v.x * v.x + v.y * v.y + v.z * v.z + v.w * v.w;
#pragma unroll
        for (int off = 32; off; off >>= 1) ssq += __shfl_xor(ssq, off, 64);
        const float rinv = 1.0f / fmaxf(sqrtf(ssq), EPSF);
        ushort4 o;
        o.x = f2bf(v.x * rinv); o.y = f2bf(v.y * rinv);
        o.z = f2bf(v.z * rinv); o.w = f2bf(v.w * rinv);
        ((ushort4*)(Enb + roff))[lane] = o;
        cp0 += v.x; cp1 += v.y; cp2 += v.z; cp3 += v.w;
    }
    cent[wid][lane * 4 + 0] = cp0;
    cent[wid][lane * 4 + 1] = cp1;
    cent[wid][lane * 4 + 2] = cp2;
    cent[wid][lane * 4 + 3] = cp3;
    __syncthreads();

    const int d = threadIdx.x;
    const float c = (cent[0][d] + cent[1][d] + cent[2][d] + cent[3][d]) * 0.1f;
    sred[d] = c * c;
    __syncthreads();
#pragma unroll
    for (int off = 128; off; off >>= 1) {
        if (d < off) sred[d] += sred[d + off];
        __syncthreads();
    }
    const float rinv = 1.0f / fmaxf(sqrtf(sred[0]), EPSF);
    Cnb[(size_t)s * DD + d] = f2bf(c * rinv);
}

// ---- Kernel 2: bf16 MFMA GEMM (Enb x Cnb^T) fused with exp-sum + pos ----
// M=20480, N=2048, K=256. Block 128x128 (2x2 waves), wave 64x64 = 2x2 tiles of
// 32x32x16 MFMA. BK=64, XOR-swizzled LDS (conflict-free b128), 2560 blocks.
#define BM 128
#define BN 128
#define BK 64

__global__ __launch_bounds__(256, 3) void gemm_lse_kernel(const unsigned short* __restrict__ Enb,
                                                          const unsigned short* __restrict__ Cnb,
                                                          float* __restrict__ posArr,
                                                          float* __restrict__ sumexp) {
    __shared__ unsigned short As[BM * BK];   // 16 KB, granule slot = g ^ (row&7)
    __shared__ unsigned short Bs[BN * BK];   // 16 KB

    const int tid  = threadIdx.x;
    const int wid  = tid >> 6, lane = tid & 63;
    const int l31  = lane & 31, h = lane >> 5;
    const int wave_m = wid >> 1, wave_n = wid & 1;

    const int bn = blockIdx.x & 15;          // SS/BN = 16
    const int bm = blockIdx.x >> 4;          // BB/BM = 160
    const int row0 = bm * BM, n0 = bn * BN;

    // staging: 32 x 1KiB chunks (A:0..15, B:16..31), 8 per wave.
    // chunk = 8 rows x 64k; lane -> row rl=lane>>3, slot lane&7 holds granule (lane&7)^rl
    const int rl = lane >> 3;
    const int g8 = ((lane & 7) ^ rl) * 8;
    const unsigned short* gp[8];
    unsigned short* lp[8];
#pragma unroll
    for (int i = 0; i < 8; ++i) {
        const int c = wid * 8 + i;
        if (c < 16) {
            gp[i] = Enb + (size_t)(row0 + c * 8 + rl) * DD + g8;
            lp[i] = As + c * 512;
        } else {
            gp[i] = Cnb + (size_t)(n0 + (c - 16) * 8 + rl) * DD + g8;
            lp[i] = Bs + (c - 16) * 512;
        }
    }

    // fragment rows (32x32x16: A row = l&31, k = h*8 + j)
    int rA[2], rB[2];
#pragma unroll
    for (int t = 0; t < 2; ++t) {
        rA[t] = wave_m * 64 + t * 32 + l31;
        rB[t] = wave_n * 64 + t * 32 + l31;
    }

    floatx16 acc[2][2] = {};

    for (int k0 = 0; k0 < DD; k0 += BK) {
        __syncthreads();                      // prior stage's LDS reads done
#pragma unroll
        for (int i = 0; i < 8; ++i) gl_lds16(gp[i] + k0, lp[i]);
        __syncthreads();                      // vmcnt drained: tiles landed
#pragma unroll
        for (int ks = 0; ks < 4; ++ks) {      // 16 k per step
            bf16x8 af[2], bfr[2];
#pragma unroll
            for (int t = 0; t < 2; ++t) {
                const int gA = ((ks * 2 + h) ^ (rA[t] & 7)) * 8;
                const int gB = ((ks * 2 + h) ^ (rB[t] & 7)) * 8;
                af[t]  = *(const bf16x8*)(As + rA[t] * BK + gA);
                bfr[t] = *(const bf16x8*)(Bs + rB[t] * BK + gB);
            }
#pragma unroll
            for (int mt = 0; mt < 2; ++mt)
#pragma unroll
                for (int nt = 0; nt < 2; ++nt)
                    acc[mt][nt] = __builtin_amdgcn_mfma_f32_32x32x16_bf16(af[mt], bfr[nt], acc[mt][nt], 0, 0, 0);
        }
    }

    // epilogue. 32x32 C/D layout: col = l&31, row = (reg&3) + 8*(reg>>2) + 4*h
#pragma unroll
    for (int mt = 0; mt < 2; ++mt) {
        float rs[16];
#pragma unroll
        for (int r = 0; r < 16; ++r) rs[r] = 0.f;
        const int growb = row0 + wave_m * 64 + mt * 32;
#pragma unroll
        for (int nt = 0; nt < 2; ++nt) {
            const int col = n0 + wave_n * 64 + nt * 32 + l31;
#pragma unroll
            for (int r = 0; r < 16; ++r) {
                const int grow = growb + (r & 3) + 8 * (r >> 2) + 4 * h;
                const float sim = acc[mt][nt][r];
                if (col == grow / UU) {
                    posArr[grow] = sim;           // excluded from sum (-inf mask)
                } else {
                    rs[r] += __expf(sim);
                }
            }
        }
#pragma unroll
        for (int m = 1; m < 32; m <<= 1) {
#pragma unroll
            for (int r = 0; r < 16; ++r) rs[r] += __shfl_xor(rs[r], m, 64);
        }
        if (l31 == 0) {
#pragma unroll
            for (int r = 0; r < 16; ++r)
                atomicAdd(&sumexp[growb + (r & 3) + 8 * (r >> 2) + 4 * h], rs[r]);
        }
    }
}

// ---- Kernel 3a: per-256-row partials of (-pos + log(sumexp)) ----
__global__ __launch_bounds__(256) void finalize1_kernel(const float* __restrict__ posArr,
                                                        const float* __restrict__ sumexp,
                                                        float* __restrict__ partials) {
    __shared__ float sred[256];
    const int tid = threadIdx.x;
    const int r = blockIdx.x * 256 + tid;
    sred[tid] = logf(sumexp[r]) - posArr[r];
    __syncthreads();
#pragma unroll
    for (int off = 128; off; off >>= 1) {
        if (tid < off) sred[tid] += sred[tid + off];
        __syncthreads();
    }
    if (tid == 0) partials[blockIdx.x] = sred[0];
}

// ---- Kernel 3b: final mean over 80 partials ----
__global__ __launch_bounds__(128) void finalize2_kernel(const float* __restrict__ partials,
                                                        float* __restrict__ out) {
    __shared__ float sred[128];
    const int tid = threadIdx.x;
    sred[tid] = (tid < BB / 256) ? partials[tid] : 0.f;
    __syncthreads();
#pragma unroll
    for (int off = 64; off; off >>= 1) {
        if (tid < off) sred[tid] += sred[tid + off];
        __syncthreads();
    }
    if (tid == 0) out[0] = sred[0] / (float)BB;
}

extern "C" void kernel_launch(void* const* d_in, const int* in_sizes, int n_in,
                              void* d_out, int out_size, void* d_ws, size_t ws_size,
                              hipStream_t stream) {
    const float* E = (const float*)d_in[0];
    float* out = (float*)d_out;

    unsigned short* Enb = (unsigned short*)d_ws;            // BB*DD bf16 = 10.5 MB
    unsigned short* Cnb = Enb + (size_t)BB * DD;            // SS*DD bf16 = 1 MB
    float* posArr  = (float*)(Cnb + (size_t)SS * DD);       // BB floats
    float* sumexp  = posArr + BB;                           // BB floats (zeroed)
    float* partials = sumexp + BB;                          // 80 floats

    hipMemsetAsync(sumexp, 0, BB * sizeof(float), stream);

    prep_kernel<<<SS, 256, 0, stream>>>(E, Enb, Cnb);
    gemm_lse_kernel<<<(BB / BM) * (SS / BN), 256, 0, stream>>>(Enb, Cnb, posArr, sumexp);
    finalize1_kernel<<<BB / 256, 256, 0, stream>>>(posArr, sumexp, partials);
    finalize2_kernel<<<1, 128, 0, stream>>>(partials, out);
}

// Round 5
// 115.499 us; speedup vs baseline: 1.1133x; 1.1133x over previous
//
#include <hip/hip_runtime.h>
#include <math.h>

// Problem constants (setup_inputs: S=2048, U=10, D=256)
#define SS   2048
#define UU   10
#define DD   256
#define BB   (SS * UU)   // 20480 rows
#define EPSF 1e-8f

typedef __attribute__((ext_vector_type(8))) short   bf16x8;
typedef __attribute__((ext_vector_type(4))) float   floatx4;

__device__ static inline unsigned short f2bf(float f) {
    union { float f; unsigned u; } v; v.f = f;
    unsigned r = (v.u + 0x7FFFu + ((v.u >> 16) & 1u)) >> 16;  // RNE
    return (unsigned short)r;
}

__device__ static inline void gl_lds16(const unsigned short* g, unsigned short* l) {
    // 16B per lane; LDS dest = wave-uniform base + lane*16
    __builtin_amdgcn_global_load_lds((const __attribute__((address_space(1))) void*)g,
                                     (__attribute__((address_space(3))) void*)l, 16, 0, 0);
}

// ---- Kernel 1 (fused prep): normalize rows -> Enb, centroid+normalize -> Cnb,
//      zero sumexp (and out) so no memset dispatch is needed ----
__global__ __launch_bounds__(256) void prep_kernel(const float* __restrict__ E,
                                                   unsigned short* __restrict__ Enb,
                                                   unsigned short* __restrict__ Cnb,
                                                   float* __restrict__ sumexp,
                                                   float* __restrict__ out) {
    const int s   = blockIdx.x;
    const int wid = threadIdx.x >> 6, lane = threadIdx.x & 63;
    __shared__ float cent[4][256];
    __shared__ float sred[256];

    if (threadIdx.x < UU) sumexp[s * UU + threadIdx.x] = 0.f;
    if (s == 0 && threadIdx.x == 0) out[0] = 0.f;

    float cp0 = 0.f, cp1 = 0.f, cp2 = 0.f, cp3 = 0.f;
    for (int u = wid; u < UU; u += 4) {
        const size_t roff = (size_t)(s * UU + u) * DD;
        float4 v = ((const float4*)(E + roff))[lane];
        float ssq = v.x * v.x + v.y * v.y + v.z * v.z + v.w * v.w;
#pragma unroll
        for (int off = 32; off; off >>= 1) ssq += __shfl_xor(ssq, off, 64);
        const float rinv = 1.0f / fmaxf(sqrtf(ssq), EPSF);
        ushort4 o;
        o.x = f2bf(v.x * rinv); o.y = f2bf(v.y * rinv);
        o.z = f2bf(v.z * rinv); o.w = f2bf(v.w * rinv);
        ((ushort4*)(Enb + roff))[lane] = o;
        cp0 += v.x; cp1 += v.y; cp2 += v.z; cp3 += v.w;
    }
    cent[wid][lane * 4 + 0] = cp0;
    cent[wid][lane * 4 + 1] = cp1;
    cent[wid][lane * 4 + 2] = cp2;
    cent[wid][lane * 4 + 3] = cp3;
    __syncthreads();

    const int d = threadIdx.x;
    const float c = (cent[0][d] + cent[1][d] + cent[2][d] + cent[3][d]) * 0.1f;
    sred[d] = c * c;
    __syncthreads();
#pragma unroll
    for (int off = 128; off; off >>= 1) {
        if (d < off) sred[d] += sred[d + off];
        __syncthreads();
    }
    const float rinv = 1.0f / fmaxf(sqrtf(sred[0]), EPSF);
    Cnb[(size_t)s * DD + d] = f2bf(c * rinv);
}

// ---- Kernel 2: bf16 MFMA GEMM (Enb x Cnb^T) fused with exp-sum + pos ----
// Round-2 core (fastest measured): 128x128 block, 2x2 waves, wave 64x64 = 4x4
// tiles of 16x16x32, BK=32. NEW: swizzled LDS — granule g of row r stored at
// slot g ^ ((r>>1)&3); 16-lane read phases tile all 8 bank-groups 2x -> free.
#define BM 128
#define BN 128
#define BK 32

__global__ __launch_bounds__(256) void gemm_lse_kernel(const unsigned short* __restrict__ Enb,
                                                       const unsigned short* __restrict__ Cnb,
                                                       float* __restrict__ posArr,
                                                       float* __restrict__ sumexp) {
    __shared__ unsigned short As[BM * BK];   // 8 KB, [row][32k] with swizzled granules
    __shared__ unsigned short Bs[BN * BK];   // 8 KB

    const int tid  = threadIdx.x;
    const int wid  = tid >> 6, lane = tid & 63;
    const int l15  = lane & 15, quad = lane >> 4;
    const int wave_m = wid >> 1, wave_n = wid & 1;

    const int bn = blockIdx.x & 15;          // SS/BN = 16 (bm-grouped order)
    const int bm = blockIdx.x >> 4;          // BB/BM = 160
    const int row0 = bm * BM, n0 = bn * BN;

    // staging: 16 chunks of 1 KB (16 rows x 32k); A: c=0..7, B: c=8..15; 4/wave.
    // lane -> row rl=lane>>2, slot sl=lane&3; fetch logical granule sl^((rl>>1)&3)
    const int rl = lane >> 2;
    const int gf = ((lane & 3) ^ ((rl >> 1) & 3)) * 8;
    const unsigned short* gp[4];
    unsigned short* lp[4];
#pragma unroll
    for (int i = 0; i < 4; ++i) {
        const int c = wid * 4 + i;
        if (c < 8) {
            gp[i] = Enb + (size_t)(row0 + c * 16 + rl) * DD + gf;
            lp[i] = As + c * 512;
        } else {
            gp[i] = Cnb + (size_t)(n0 + (c - 8) * 16 + rl) * DD + gf;
            lp[i] = Bs + (c - 8) * 512;
        }
    }

    // fragment offsets: row r = wtile*16 + l15, elem = r*BK + (quad^((l15>>1)&3))*8
    const int fswz = (quad ^ ((l15 >> 1) & 3)) * 8;
    int aoff[4], boff[4];
#pragma unroll
    for (int t = 0; t < 4; ++t) {
        aoff[t] = (wave_m * 64 + t * 16 + l15) * BK + fswz;
        boff[t] = (wave_n * 64 + t * 16 + l15) * BK + fswz;
    }

    floatx4 acc[4][4];
#pragma unroll
    for (int i = 0; i < 4; ++i)
#pragma unroll
        for (int j = 0; j < 4; ++j) acc[i][j] = (floatx4){0.f, 0.f, 0.f, 0.f};

    for (int k0 = 0; k0 < DD; k0 += BK) {
        __syncthreads();                      // prior stage's LDS reads done
#pragma unroll
        for (int i = 0; i < 4; ++i) gl_lds16(gp[i] + k0, lp[i]);
        __syncthreads();                      // vmcnt drained: tiles landed

        bf16x8 af[4], bfr[4];
#pragma unroll
        for (int t = 0; t < 4; ++t) af[t]  = *(const bf16x8*)(As + aoff[t]);
#pragma unroll
        for (int t = 0; t < 4; ++t) bfr[t] = *(const bf16x8*)(Bs + boff[t]);
#pragma unroll
        for (int mt = 0; mt < 4; ++mt)
#pragma unroll
            for (int nt = 0; nt < 4; ++nt)
                acc[mt][nt] = __builtin_amdgcn_mfma_f32_16x16x32_bf16(af[mt], bfr[nt], acc[mt][nt], 0, 0, 0);
    }

    // epilogue: C/D layout col=l15 (n), row=quad*4+reg (m)
#pragma unroll
    for (int mt = 0; mt < 4; ++mt) {
        float rs[4] = {0.f, 0.f, 0.f, 0.f};
        const int growb = row0 + wave_m * 64 + mt * 16 + quad * 4;
#pragma unroll
        for (int nt = 0; nt < 4; ++nt) {
            const int col = n0 + wave_n * 64 + nt * 16 + l15;
#pragma unroll
            for (int r = 0; r < 4; ++r) {
                const int grow = growb + r;
                const float sim = acc[mt][nt][r];
                if (col == grow / UU) {
                    posArr[grow] = sim;           // excluded from sum (-inf mask)
                } else {
                    rs[r] += __expf(sim);
                }
            }
        }
#pragma unroll
        for (int m = 1; m < 16; m <<= 1) {
#pragma unroll
            for (int r = 0; r < 4; ++r) rs[r] += __shfl_xor(rs[r], m, 64);
        }
        if (l15 == 0) {
#pragma unroll
            for (int r = 0; r < 4; ++r) atomicAdd(&sumexp[growb + r], rs[r]);
        }
    }
}

// ---- Kernel 3: single-pass finalize: mean of (-pos + log(sumexp)) ----
__global__ __launch_bounds__(256) void finalize_kernel(const float* __restrict__ posArr,
                                                       const float* __restrict__ sumexp,
                                                       float* __restrict__ out) {
    __shared__ float sred[256];
    const int tid = threadIdx.x;
    const int r = blockIdx.x * 256 + tid;
    sred[tid] = logf(sumexp[r]) - posArr[r];
    __syncthreads();
#pragma unroll
    for (int off = 128; off; off >>= 1) {
        if (tid < off) sred[tid] += sred[tid + off];
        __syncthreads();
    }
    if (tid == 0) atomicAdd(out, sred[0] * (1.0f / (float)BB));
}

extern "C" void kernel_launch(void* const* d_in, const int* in_sizes, int n_in,
                              void* d_out, int out_size, void* d_ws, size_t ws_size,
                              hipStream_t stream) {
    const float* E = (const float*)d_in[0];
    float* out = (float*)d_out;

    unsigned short* Enb = (unsigned short*)d_ws;            // BB*DD bf16 = 10.5 MB
    unsigned short* Cnb = Enb + (size_t)BB * DD;            // SS*DD bf16 = 1 MB
    float* posArr = (float*)(Cnb + (size_t)SS * DD);        // BB floats
    float* sumexp = posArr + BB;                            // BB floats (zeroed by prep)

    prep_kernel<<<SS, 256, 0, stream>>>(E, Enb, Cnb, sumexp, out);
    gemm_lse_kernel<<<(BB / BM) * (SS / BN), 256, 0, stream>>>(Enb, Cnb, posArr, sumexp);
    finalize_kernel<<<BB / 256, 256, 0, stream>>>(posArr, sumexp, out);
}